// Round 4
// baseline (183.349 us; speedup 1.0000x reference)
//
#include <hip/hip_runtime.h>

// BERT lattice embedding: ragged segment mean-pool.
// hidden: [B,S,H] f32, word_ids: [B,S] i32 (non-decreasing per sample),
// out: [B,T,H] f32 with out[b,t,:] = mean over the contiguous run of s with
// word_ids[b,s]==t (zeros if the run is empty).
//
// R3 design: R2 streaming structure + deep memory-level parallelism.
// One 192-thread block (3 waves) per (b, 16-word chunk); the chunk's pieces
// occupy one contiguous disjoint row span, read exactly once, sequentially.
// NEW: rows are loaded in unconditional batches of 8 into a register buffer
// (8 independent 16B loads in flight per thread, ~8 KB/wave) before the
// run-boundary accumulate pass consumes them. This is the MLP depth R0-R2
// lacked (1-3 KB/wave -> observed ~2 TB/s latency-bound plateau).
// Output stores are nontemporal (write-once stream) to keep L2 for reads.

#define BB 64
#define SS 512
#define HH 768
#define TT 400
#define TCHUNK 16
#define NCHUNK (TT / TCHUNK)     // 25
#define NTHR 192                 // 3 waves; 192 float4 = 768 floats = H
#define H4 (HH / 4)              // 192
#define BATCH 8

typedef float f32x4 __attribute__((ext_vector_type(4)));

__global__ __launch_bounds__(NTHR) void bert_lattice_pool_kernel(
    const float* __restrict__ hidden,
    const int* __restrict__ word_ids,
    float* __restrict__ out)
{
    __shared__ int wid[SS];
    __shared__ int sstart[TCHUNK];
    __shared__ int send[TCHUNK];
    __shared__ int spanlo_s;
    __shared__ int spanhi_s;

    const int blk = blockIdx.x;             // b * NCHUNK + chunk
    const int b   = blk / NCHUNK;
    const int t0  = (blk - b * NCHUNK) * TCHUNK;
    const int t1  = t0 + TCHUNK;
    const int tid = threadIdx.x;

    // Stage word_ids row into LDS with int4 loads (128 threads x 16B = 2KB).
    if (tid < SS / 4) {
        reinterpret_cast<int4*>(wid)[tid] =
            reinterpret_cast<const int4*>(word_ids + b * SS)[tid];
    }
    if (tid < TCHUNK) { sstart[tid] = 0; send[tid] = 0; }
    if (tid == 0) { spanlo_s = SS; spanhi_s = 0; }
    __syncthreads();

    // Parallel boundary scatter (unique writer per slot — runs are contiguous).
    for (int s = tid; s < SS; s += NTHR) {
        const int w = wid[s];
        if (w >= t0 && w < t1) {
            if (s == 0      || wid[s - 1] != w) sstart[w - t0] = s;
            if (s == SS - 1 || wid[s + 1] != w) send[w - t0]   = s + 1;
            if (s == 0      || wid[s - 1] < t0) spanlo_s = s;
        }
        if (w < t1 && (s == SS - 1 || wid[s + 1] >= t1)) spanhi_s = s + 1;
    }
    __syncthreads();

    const int spanlo = spanlo_s;
    const int spanhi = spanhi_s;   // empty chunk: spanlo=SS >= spanhi

    const f32x4* hbase = reinterpret_cast<const f32x4*>(hidden) + (size_t)b * SS * H4;
    f32x4*       obase = reinterpret_cast<f32x4*>(out)          + (size_t)b * TT * H4;

    if (spanlo < spanhi) {
        f32x4 acc = {0.f, 0.f, 0.f, 0.f};
        int run_start = spanlo;

        for (int s0 = spanlo; s0 < spanhi; s0 += BATCH) {
            // Phase 1: issue BATCH independent loads (tail clamps address only;
            // clamped rows are never accumulated).
            f32x4 v[BATCH];
            #pragma unroll
            for (int i = 0; i < BATCH; ++i) {
                int s = s0 + i;
                s = (s < spanhi) ? s : (spanhi - 1);
                v[i] = hbase[(size_t)s * H4 + tid];
            }
            // Phase 2: consume in order with block-uniform run-boundary logic.
            #pragma unroll
            for (int i = 0; i < BATCH; ++i) {
                const int s = s0 + i;
                if (s >= spanhi) break;              // uniform
                acc += v[i];
                const int w = wid[s];                // block-uniform
                const bool endrun = (s + 1 == spanhi) || (wid[s + 1] != w);
                if (endrun) {                        // uniform
                    const float inv = 1.0f / (float)(s - run_start + 1);
                    f32x4 r = acc * inv;
                    __builtin_nontemporal_store(r, &obase[(size_t)w * H4 + tid]);
                    acc = (f32x4){0.f, 0.f, 0.f, 0.f};
                    run_start = s + 1;
                }
            }
        }
    }

    // Zero-fill words with no pieces (sstart==send only when empty).
    #pragma unroll
    for (int rel = 0; rel < TCHUNK; ++rel) {
        if (send[rel] == sstart[rel]) {
            f32x4 z = {0.f, 0.f, 0.f, 0.f};
            __builtin_nontemporal_store(z, &obase[(size_t)(t0 + rel) * H4 + tid]);
        }
    }
}

extern "C" void kernel_launch(void* const* d_in, const int* in_sizes, int n_in,
                              void* d_out, int out_size, void* d_ws, size_t ws_size,
                              hipStream_t stream) {
    (void)in_sizes; (void)n_in; (void)d_ws; (void)ws_size; (void)out_size;
    const float* hidden   = (const float*)d_in[0];
    const int*   word_ids = (const int*)d_in[1];
    float*       out      = (float*)d_out;

    dim3 grid(BB * NCHUNK);   // 64 * 25 = 1600 blocks
    dim3 block(NTHR);
    bert_lattice_pool_kernel<<<grid, block, 0, stream>>>(hidden, word_ids, out);
}

// Round 5
// 177.569 us; speedup vs baseline: 1.0325x; 1.0325x over previous
//
#include <hip/hip_runtime.h>

// BERT lattice embedding: ragged segment mean-pool.
// hidden: [B,S,H] f32, word_ids: [B,S] i32 (non-decreasing per sample),
// out: [B,T,H] f32 with out[b,t,:] = mean over the contiguous run of s with
// word_ids[b,s]==t (zeros if the run is empty).
//
// R4: two-kernel, max-TLP / min-dependency-depth design.
//  A) build_table: one block per sample; LDS boundary scatter -> packed
//     (start | cnt<<16) per (b,t) into d_ws. ~100 KB, ~3 us.
//  B) pool: ONE WAVE PER OUTPUT ROW, 256-thread blocks (6400 blocks ->
//     up to 32 waves/CU resident, vs 12-20 in R0-R3). Per-wave critical
//     path: 1 uniform table load -> 3 independent float4 loads (x cnt,
//     avg 1.28) -> 3 nontemporal stores. No LDS, no barriers, no serial
//     span loop. Copy-kernel shape applied to the gather.

#define BB 64
#define SS 512
#define HH 768
#define TT 400
#define H4 (HH / 4)              // 192 float4 per row

typedef float f32x4 __attribute__((ext_vector_type(4)));

// ---------- Kernel A: per-(b,t) run table ----------
__global__ __launch_bounds__(256) void build_table_kernel(
    const int* __restrict__ word_ids,
    int* __restrict__ table)          // [BB*TT] packed: start | (cnt<<16)
{
    __shared__ int wid[SS];
    __shared__ int sstart[TT];
    __shared__ int send[TT];

    const int b   = blockIdx.x;
    const int tid = threadIdx.x;

    if (tid < SS / 4) {
        reinterpret_cast<int4*>(wid)[tid] =
            reinterpret_cast<const int4*>(word_ids + b * SS)[tid];
    }
    for (int t = tid; t < TT; t += 256) { sstart[t] = 0; send[t] = 0; }
    __syncthreads();

    for (int s = tid; s < SS; s += 256) {
        const int w = wid[s];                       // w in [0, TT)
        if (s == 0      || wid[s - 1] != w) sstart[w] = s;
        if (s == SS - 1 || wid[s + 1] != w) send[w]   = s + 1;
    }
    __syncthreads();

    for (int t = tid; t < TT; t += 256) {
        const int st  = sstart[t];
        const int cnt = send[t] - st;               // empty word: 0-0 = 0
        table[b * TT + t] = st | (cnt << 16);
    }
}

// ---------- Kernel B: one wave per output row ----------
__global__ __launch_bounds__(256) void pool_kernel(
    const float* __restrict__ hidden,
    const int* __restrict__ table,
    float* __restrict__ out)
{
    const int wave = threadIdx.x >> 6;
    const int lane = threadIdx.x & 63;
    const int bt   = blockIdx.x * 4 + wave;         // 0 .. BB*TT-1
    const int b    = bt / TT;

    const int pack  = table[bt];                    // wave-uniform, one line
    const int start = pack & 0xFFFF;
    const int cnt   = pack >> 16;

    const f32x4* hrow = reinterpret_cast<const f32x4*>(hidden)
                        + ((size_t)b * SS + start) * H4;
    f32x4* orow = reinterpret_cast<f32x4*>(out) + (size_t)bt * H4;

    f32x4 a0 = {0.f, 0.f, 0.f, 0.f};
    f32x4 a1 = {0.f, 0.f, 0.f, 0.f};
    f32x4 a2 = {0.f, 0.f, 0.f, 0.f};

    for (int i = 0; i < cnt; ++i) {                 // wave-uniform trip count
        const f32x4* p = hrow + (size_t)i * H4;
        a0 += p[lane];
        a1 += p[lane + 64];
        a2 += p[lane + 128];
    }

    const float inv = (cnt > 1) ? (1.0f / (float)cnt) : 1.0f;
    a0 *= inv; a1 *= inv; a2 *= inv;

    __builtin_nontemporal_store(a0, &orow[lane]);
    __builtin_nontemporal_store(a1, &orow[lane + 64]);
    __builtin_nontemporal_store(a2, &orow[lane + 128]);
}

extern "C" void kernel_launch(void* const* d_in, const int* in_sizes, int n_in,
                              void* d_out, int out_size, void* d_ws, size_t ws_size,
                              hipStream_t stream) {
    (void)in_sizes; (void)n_in; (void)ws_size; (void)out_size;
    const float* hidden   = (const float*)d_in[0];
    const int*   word_ids = (const int*)d_in[1];
    float*       out      = (float*)d_out;
    int*         table    = (int*)d_ws;             // BB*TT*4 = 100 KB

    build_table_kernel<<<dim3(BB), dim3(256), 0, stream>>>(word_ids, table);
    pool_kernel<<<dim3(BB * TT / 4), dim3(256), 0, stream>>>(hidden, table, out);
}